// Round 7
// baseline (296.349 us; speedup 1.0000x reference)
//
#include <hip/hip_runtime.h>
#include <hip/hip_bf16.h>
#include <math.h>

#define N_NODES 6144
#define NFEAT 512
#define NHID 256
#define NHEADS 4
#define DHEAD 64
#define NEMBED 128
#define LRELU_ALPHA 0.2f
#define MAXC 256          // CSR capacity/row; degree ~Binom(6144,1%): mean 61.4, sd 7.8, P(c>128)~1e-17
#define ASTRIDE 20        // out_gemm As row pad

typedef __attribute__((ext_vector_type(8))) __bf16 bfrag;   // MFMA A/B operand (4 VGPRs)
typedef __attribute__((ext_vector_type(4))) float f32x4;    // MFMA C/D operand

// round-to-nearest-even fp32 -> bf16 (bit pattern)
static __device__ __forceinline__ unsigned short f2bf(float f) {
    unsigned u = __float_as_uint(f);
    unsigned r = (u + 0x7FFFu + ((u >> 16) & 1u)) >> 16;
    return (unsigned short)r;
}
static __device__ __forceinline__ float bf2f(unsigned short b) {
    return __uint_as_float((unsigned)b << 16);
}
// Markidis split: v ~= hi + lo, each bf16
static __device__ __forceinline__ void split1(float v, unsigned short& h, unsigned short& l) {
    h = f2bf(v);
    l = f2bf(v - bf2f(h));
}
static __device__ __forceinline__ float bfLo(unsigned u) { return __uint_as_float(u << 16); }
static __device__ __forceinline__ float bfHi(unsigned u) { return __uint_as_float(u & 0xffff0000u); }

// ---------------------------------------------------------------------------
// Kernel 1a: dedicated CSR scan. ONE adjacency row per block, LDS-atomic count.
// Standalone so its VGPR count (~24) is not inflated by the MFMA path ->
// 8 blocks/CU resident -> enough loads in flight to run at the HBM fill rate.
// ---------------------------------------------------------------------------
__global__ __launch_bounds__(256) void scan_csr(const int* __restrict__ adj,
                                                int* __restrict__ cnt_g,
                                                unsigned short* __restrict__ nbr_g) {
    __shared__ int scnt;
    const int tid = threadIdx.x;
    const int r = blockIdx.x;
    const int* arow = adj + (size_t)r * N_NODES;
    unsigned short* nrow = nbr_g + (size_t)r * MAXC;
    if (tid == 0) scnt = 0;
    __syncthreads();
#pragma unroll
    for (int it = 0; it < 6; ++it) {
        const int j0 = it * 1024 + tid * 4;
        const int4 v = *(const int4*)(arow + j0);
        const int n = (v.x != 0) + (v.y != 0) + (v.z != 0) + (v.w != 0);
        if (n) {
            int base = atomicAdd(&scnt, n);
            if (v.x) { if (base < MAXC) nrow[base] = (unsigned short)j0; ++base; }
            if (v.y) { if (base < MAXC) nrow[base] = (unsigned short)(j0 + 1); ++base; }
            if (v.z) { if (base < MAXC) nrow[base] = (unsigned short)(j0 + 2); ++base; }
            if (v.w) { if (base < MAXC) nrow[base] = (unsigned short)(j0 + 3); }
        }
    }
    __syncthreads();
    if (tid == 0) cnt_g[r] = scnt;
}

// ---------------------------------------------------------------------------
// Kernel 1b: pure MFMA GEMM, grid (96, 4). [R5 kernel, verified]
// Wh[h]=x.W[h] via split-bf16 MFMA; fused s/t epilogue; Whb stored bf16.
// ---------------------------------------------------------------------------
__global__ __launch_bounds__(256) void gemm_k1(const float* __restrict__ x,
                                               const float* __restrict__ W,
                                               const float* __restrict__ a_src,
                                               const float* __restrict__ a_dst,
                                               unsigned short* __restrict__ Whb,
                                               float* __restrict__ s_arr,
                                               float* __restrict__ t_arr) {
    __shared__ unsigned short Ah[64][32];   // x-tile hi  (rows x k)
    __shared__ unsigned short Al[64][32];   // x-tile lo
    __shared__ unsigned short Bh[64][32];   // W-tile hi, TRANSPOSED (n x k), k-block swizzled
    __shared__ unsigned short Bl[64][32];   // W-tile lo
    const int tid = threadIdx.x;

    const int h = blockIdx.y;
    const int row0 = blockIdx.x * 64;
    const int w = tid >> 6;           // wave id: rows [w*16, w*16+16)
    const int lane = tid & 63;
    const int g = lane >> 4;          // lane group
    const int r = lane & 15;          // lane row-in-group
    const float* Bp = W + (size_t)h * NFEAT * DHEAD;

    f32x4 acc[4] = {};                // acc[nt]: cols nt*16+r, rows w*16+4g+q

    const int ar = tid >> 2, akq = (tid & 3) * 8;      // A: row, k-oct base
    const int bkk = tid >> 3, bnq = tid & 7;           // B: k, n-oct
    const int bks = bkk ^ ((bnq & 3) << 3);            // swizzled k-column for B writes

    for (int k0 = 0; k0 < NFEAT; k0 += 32) {
        const float4 av0 = *(const float4*)(x + (size_t)(row0 + ar) * NFEAT + k0 + akq);
        const float4 av1 = *(const float4*)(x + (size_t)(row0 + ar) * NFEAT + k0 + akq + 4);
        ushort4 h0, l0, h1, l1;
        split1(av0.x, h0.x, l0.x); split1(av0.y, h0.y, l0.y);
        split1(av0.z, h0.z, l0.z); split1(av0.w, h0.w, l0.w);
        split1(av1.x, h1.x, l1.x); split1(av1.y, h1.y, l1.y);
        split1(av1.z, h1.z, l1.z); split1(av1.w, h1.w, l1.w);
        *(ushort4*)&Ah[ar][akq]     = h0;
        *(ushort4*)&Ah[ar][akq + 4] = h1;
        *(ushort4*)&Al[ar][akq]     = l0;
        *(ushort4*)&Al[ar][akq + 4] = l1;
        const float4 bv0 = *(const float4*)(Bp + (size_t)(k0 + bkk) * DHEAD + bnq * 8);
        const float4 bv1 = *(const float4*)(Bp + (size_t)(k0 + bkk) * DHEAD + bnq * 8 + 4);
        {
            unsigned short hh, ll;
            split1(bv0.x, hh, ll); Bh[bnq * 8 + 0][bks] = hh; Bl[bnq * 8 + 0][bks] = ll;
            split1(bv0.y, hh, ll); Bh[bnq * 8 + 1][bks] = hh; Bl[bnq * 8 + 1][bks] = ll;
            split1(bv0.z, hh, ll); Bh[bnq * 8 + 2][bks] = hh; Bl[bnq * 8 + 2][bks] = ll;
            split1(bv0.w, hh, ll); Bh[bnq * 8 + 3][bks] = hh; Bl[bnq * 8 + 3][bks] = ll;
            split1(bv1.x, hh, ll); Bh[bnq * 8 + 4][bks] = hh; Bl[bnq * 8 + 4][bks] = ll;
            split1(bv1.y, hh, ll); Bh[bnq * 8 + 5][bks] = hh; Bl[bnq * 8 + 5][bks] = ll;
            split1(bv1.z, hh, ll); Bh[bnq * 8 + 6][bks] = hh; Bl[bnq * 8 + 6][bks] = ll;
            split1(bv1.w, hh, ll); Bh[bnq * 8 + 7][bks] = hh; Bl[bnq * 8 + 7][bks] = ll;
        }
        __syncthreads();
        const int arow = w * 16 + r;
        const bfrag ah = *(const bfrag*)&Ah[arow][g * 8];
        const bfrag al = *(const bfrag*)&Al[arow][g * 8];
#pragma unroll
        for (int nt = 0; nt < 4; nt++) {
            const int blk = (g ^ ((2 * nt + (r >> 3)) & 3)) * 8;
            const bfrag bh = *(const bfrag*)&Bh[nt * 16 + r][blk];
            const bfrag bl = *(const bfrag*)&Bl[nt * 16 + r][blk];
            acc[nt] = __builtin_amdgcn_mfma_f32_16x16x32_bf16(ah, bh, acc[nt], 0, 0, 0);
            acc[nt] = __builtin_amdgcn_mfma_f32_16x16x32_bf16(ah, bl, acc[nt], 0, 0, 0);
            acc[nt] = __builtin_amdgcn_mfma_f32_16x16x32_bf16(al, bh, acc[nt], 0, 0, 0);
        }
        __syncthreads();
    }
    float asv[4], adv[4];
#pragma unroll
    for (int nt = 0; nt < 4; nt++) {
        asv[nt] = a_src[h * DHEAD + nt * 16 + r];
        adv[nt] = a_dst[h * DHEAD + nt * 16 + r];
    }
    const int mbase = row0 + w * 16 + 4 * g;
#pragma unroll
    for (int q = 0; q < 4; q++) {
        const int m = mbase + q;
#pragma unroll
        for (int nt = 0; nt < 4; nt++)
            Whb[((size_t)h * N_NODES + m) * DHEAD + nt * 16 + r] = f2bf(acc[nt][q]);
        float ps = acc[0][q] * asv[0] + acc[1][q] * asv[1] +
                   acc[2][q] * asv[2] + acc[3][q] * asv[3];
        float pt = acc[0][q] * adv[0] + acc[1][q] * adv[1] +
                   acc[2][q] * adv[2] + acc[3][q] * adv[3];
#pragma unroll
        for (int off = 1; off < 16; off <<= 1) {
            ps += __shfl_xor(ps, off);
            pt += __shfl_xor(pt, off);
        }
        if (r == 0) {
            s_arr[h * N_NODES + m] = ps;
            t_arr[h * N_NODES + m] = pt;
        }
    }
}

// ---------------------------------------------------------------------------
// Kernel 2: WAVE-PER-NODE attention. Block = 4 nodes (one per wave), ZERO
// barriers, zero cross-lane output reduction.
//   lane = (g, r): g = lane>>4 = head, r = lane&15 = d-slice (d = 4r..4r+3).
//   Neighbor indices held in 2 VGPRs (c <= 128 covers all rows at 1% density;
//   P(c>128) ~ 1e-17). Softmax: lane (g,r) computes e for k = r+16*it, reduce
//   over 16-lane group (4 shuffle steps). p staged in wave-private LDS
//   (padded stride 132 -> conflict-free). Gather: one dwordx2 wave-load per
//   neighbor covers all 4 heads x 64 dims; each lane accumulates & writes its
//   own d-slice -> no combine shuffles at all.
// ---------------------------------------------------------------------------
__global__ __launch_bounds__(256) void attn_agg(const int* __restrict__ adj,
                                                const unsigned short* __restrict__ Whb,
                                                const float* __restrict__ s_arr,
                                                const float* __restrict__ t_arr,
                                                const int* __restrict__ cnt_g,
                                                const unsigned short* __restrict__ nbr_g,
                                                float* __restrict__ hcat) {
    __shared__ float p_lds[4][4][132];   // [wave][head][k], pad 132 kills 4-way write conflict
    const int tid = threadIdx.x;
    const int w = tid >> 6;
    const int lane = tid & 63;
    const int g = lane >> 4;          // head
    const int r = lane & 15;          // d-slice: d = 4r..4r+3
    const int i = blockIdx.x * 4 + w; // node
    const int c = cnt_g[i];
    const unsigned short* wp = Whb + (size_t)g * N_NODES * DHEAD;
    const unsigned short* nrow = nbr_g + (size_t)i * MAXC;
    const int dofs = r * 4;

    float a0[4] = {0.f, 0.f, 0.f, 0.f};
    float a1[4] = {0.f, 0.f, 0.f, 0.f};
    float l = 1.0f;

    if (c > 0 && c <= 128) {
        // neighbor list -> 2 registers/lane (entries past c are garbage, never used)
        const int nj0 = nrow[lane];
        const int nj1 = nrow[64 + lane];
        const float s_h = s_arr[g * N_NODES + i];
        const float* tp = t_arr + (size_t)g * N_NODES;

        // ---- softmax logits: lane (g,r) owns k = r + 16*it ----
        float ev[8];
        float m = -INFINITY;
#pragma unroll
        for (int it = 0; it < 8; it++) {
            const int k = r + 16 * it;
            const int j = (it < 4) ? __shfl(nj0, k) : __shfl(nj1, k - 64);
            float e = -INFINITY;
            if (k < c) {
                e = s_h + tp[j];
                e = e >= 0.0f ? e : LRELU_ALPHA * e;
            }
            ev[it] = e;
            m = fmaxf(m, e);
        }
#pragma unroll
        for (int off = 1; off < 16; off <<= 1) m = fmaxf(m, __shfl_xor(m, off));
        float ls = 0.0f;
#pragma unroll
        for (int it = 0; it < 8; it++) {
            const int k = r + 16 * it;
            if (k < c) {
                const float p = __expf(ev[it] - m);
                ls += p;
                p_lds[w][g][k] = p;
            }
        }
#pragma unroll
        for (int off = 1; off < 16; off <<= 1) ls += __shfl_xor(ls, off);
        l = ls;
        // wave-private LDS: in-order within wave, no barrier needed.

        // ---- gather: one wave-load per neighbor (all heads at once) ----
        const int c0 = c < 64 ? c : 64;
        int j = 0;
        for (; j + 4 <= c0; j += 4) {
            const int ja = __shfl(nj0, j),     jb = __shfl(nj0, j + 1);
            const int jc = __shfl(nj0, j + 2), jd = __shfl(nj0, j + 3);
            const float pa = p_lds[w][g][j],     pb = p_lds[w][g][j + 1];
            const float pc = p_lds[w][g][j + 2], pd = p_lds[w][g][j + 3];
            const uint2 wa = *(const uint2*)(wp + (size_t)ja * DHEAD + dofs);
            const uint2 wb = *(const uint2*)(wp + (size_t)jb * DHEAD + dofs);
            const uint2 wc = *(const uint2*)(wp + (size_t)jc * DHEAD + dofs);
            const uint2 wd = *(const uint2*)(wp + (size_t)jd * DHEAD + dofs);
            a0[0] += pa * bfLo(wa.x); a0[1] += pa * bfHi(wa.x);
            a0[2] += pa * bfLo(wa.y); a0[3] += pa * bfHi(wa.y);
            a1[0] += pb * bfLo(wb.x); a1[1] += pb * bfHi(wb.x);
            a1[2] += pb * bfLo(wb.y); a1[3] += pb * bfHi(wb.y);
            a0[0] += pc * bfLo(wc.x); a0[1] += pc * bfHi(wc.x);
            a0[2] += pc * bfLo(wc.y); a0[3] += pc * bfHi(wc.y);
            a1[0] += pd * bfLo(wd.x); a1[1] += pd * bfHi(wd.x);
            a1[2] += pd * bfLo(wd.y); a1[3] += pd * bfHi(wd.y);
        }
        for (; j < c0; j++) {
            const int ja = __shfl(nj0, j);
            const float pa = p_lds[w][g][j];
            const uint2 wa = *(const uint2*)(wp + (size_t)ja * DHEAD + dofs);
            a0[0] += pa * bfLo(wa.x); a0[1] += pa * bfHi(wa.x);
            a0[2] += pa * bfLo(wa.y); a0[3] += pa * bfHi(wa.y);
        }
        for (j = 64; j + 2 <= c; j += 2) {
            const int ja = __shfl(nj1, j - 64), jb = __shfl(nj1, j - 63);
            const float pa = p_lds[w][g][j], pb = p_lds[w][g][j + 1];
            const uint2 wa = *(const uint2*)(wp + (size_t)ja * DHEAD + dofs);
            const uint2 wb = *(const uint2*)(wp + (size_t)jb * DHEAD + dofs);
            a0[0] += pa * bfLo(wa.x); a0[1] += pa * bfHi(wa.x);
            a0[2] += pa * bfLo(wa.y); a0[3] += pa * bfHi(wa.y);
            a1[0] += pb * bfLo(wb.x); a1[1] += pb * bfHi(wb.x);
            a1[2] += pb * bfLo(wb.y); a1[3] += pb * bfHi(wb.y);
        }
        if (j < c) {
            const int ja = __shfl(nj1, j - 64);
            const float pa = p_lds[w][g][j];
            const uint2 wa = *(const uint2*)(wp + (size_t)ja * DHEAD + dofs);
            a0[0] += pa * bfLo(wa.x); a0[1] += pa * bfHi(wa.x);
            a0[2] += pa * bfLo(wa.y); a0[3] += pa * bfHi(wa.y);
        }
    } else if (c == 0) {
        // empty row: softmax over uniform -9e15 logits -> mean of Wh (never at 1%)
        for (int j = 0; j < N_NODES; j++) {
            const uint2 wv = *(const uint2*)(wp + (size_t)j * DHEAD + dofs);
            a0[0] += bfLo(wv.x); a0[1] += bfHi(wv.x);
            a0[2] += bfLo(wv.y); a0[3] += bfHi(wv.y);
        }
        l = (float)N_NODES;
    } else {
        // 128 < c: online-softmax over CSR list (c<=MAXC) or full adj row (c>MAXC)
        const float s_h = s_arr[g * N_NODES + i];
        const float* tp = t_arr + (size_t)g * N_NODES;
        float m = -INFINITY, ll = 0.0f;
        if (c <= MAXC) {
            for (int k = 0; k < c; k++) {
                const int j = nrow[k];
                float e = s_h + tp[j];
                e = e >= 0.0f ? e : LRELU_ALPHA * e;
                const float mn = fmaxf(m, e);
                const float sc = __expf(m - mn), p = __expf(e - mn);
                ll = ll * sc + p;
                const uint2 wv = *(const uint2*)(wp + (size_t)j * DHEAD + dofs);
                a0[0] = a0[0] * sc + p * bfLo(wv.x);
                a0[1] = a0[1] * sc + p * bfHi(wv.x);
                a0[2] = a0[2] * sc + p * bfLo(wv.y);
                a0[3] = a0[3] * sc + p * bfHi(wv.y);
                m = mn;
            }
        } else {
            const int* arow = adj + (size_t)i * N_NODES;
            for (int j = 0; j < N_NODES; j++) {
                if (arow[j]) {
                    float e = s_h + tp[j];
                    e = e >= 0.0f ? e : LRELU_ALPHA * e;
                    const float mn = fmaxf(m, e);
                    const float sc = __expf(m - mn), p = __expf(e - mn);
                    ll = ll * sc + p;
                    const uint2 wv = *(const uint2*)(wp + (size_t)j * DHEAD + dofs);
                    a0[0] = a0[0] * sc + p * bfLo(wv.x);
                    a0[1] = a0[1] * sc + p * bfHi(wv.x);
                    a0[2] = a0[2] * sc + p * bfLo(wv.y);
                    a0[3] = a0[3] * sc + p * bfHi(wv.y);
                    m = mn;
                }
            }
        }
        l = ll;
    }

    // per-head ELU; each lane owns d = 4r..4r+3 of head g -> direct float4 store
    float4 hv;
#pragma unroll
    for (int d = 0; d < 4; d++) {
        float v = (a0[d] + a1[d]) / l;
        (&hv.x)[d] = v > 0.0f ? v : expm1f(v);
    }
    *(float4*)(hcat + (size_t)i * NHID + g * DHEAD + dofs) = hv;
}

// ---------------------------------------------------------------------------
// Kernel 3: out = elu(hcat @ lin_w^T + b)
// ---------------------------------------------------------------------------
__global__ __launch_bounds__(256) void out_gemm(const float* __restrict__ hcat,
                                                const float* __restrict__ lin_w,
                                                const float* __restrict__ lin_b,
                                                float* __restrict__ out) {
    __shared__ float As[64][ASTRIDE * 4];
    __shared__ float Bs[16][64];
    const int tid = threadIdx.x;
    const int tx = tid & 15;
    const int ty = tid >> 4;
    const int row0 = blockIdx.x * 64;
    const int c0 = blockIdx.y * 64;

    float acc[4][4] = {};

    for (int k0 = 0; k0 < NHID; k0 += 16) {
        {
            const int r = tid >> 2, kq = tid & 3;
            const float4 v = *(const float4*)(hcat + (size_t)(row0 + r) * NHID + k0 + kq * 4);
            *(float4*)&As[r][kq * 4] = v;
        }
        {
            const int cc = tid & 63, kq = tid >> 6;
            const float4 v = *(const float4*)(lin_w + (size_t)(c0 + cc) * NHID + k0 + kq * 4);
            Bs[kq * 4 + 0][cc] = v.x;
            Bs[kq * 4 + 1][cc] = v.y;
            Bs[kq * 4 + 2][cc] = v.z;
            Bs[kq * 4 + 3][cc] = v.w;
        }
        __syncthreads();
#pragma unroll
        for (int kk = 0; kk < 16; kk++) {
            float a[4], b[4];
#pragma unroll
            for (int i = 0; i < 4; i++) a[i] = As[ty * 4 + i][kk];
#pragma unroll
            for (int j = 0; j < 4; j++) b[j] = Bs[kk][tx * 4 + j];
#pragma unroll
            for (int i = 0; i < 4; i++)
#pragma unroll
                for (int j = 0; j < 4; j++) acc[i][j] += a[i] * b[j];
        }
        __syncthreads();
    }
#pragma unroll
    for (int i = 0; i < 4; i++) {
        const int row = row0 + ty * 4 + i;
        float v[4];
#pragma unroll
        for (int j = 0; j < 4; j++) {
            const int col = c0 + tx * 4 + j;
            float val = acc[i][j] + lin_b[col];
            v[j] = val > 0.0f ? val : expm1f(val);
        }
        *(float4*)(out + (size_t)row * NEMBED + c0 + tx * 4) =
            make_float4(v[0], v[1], v[2], v[3]);
    }
}

extern "C" void kernel_launch(void* const* d_in, const int* in_sizes, int n_in,
                              void* d_out, int out_size, void* d_ws, size_t ws_size,
                              hipStream_t stream) {
    const float* x     = (const float*)d_in[0];
    const int*   adj   = (const int*)d_in[1];
    const float* W     = (const float*)d_in[2];
    const float* a_src = (const float*)d_in[3];
    const float* a_dst = (const float*)d_in[4];
    const float* lin_w = (const float*)d_in[5];
    const float* lin_b = (const float*)d_in[6];
    float* out = (float*)d_out;

    unsigned short* Whb = (unsigned short*)d_ws;                  // H*N*D bf16 (3.1 MB)
    float* s    = (float*)(Whb + (size_t)NHEADS * N_NODES * DHEAD);
    float* t    = s + (size_t)NHEADS * N_NODES;
    float* hcat = t + (size_t)NHEADS * N_NODES;                   // N*NHID floats
    int* cnt_g  = (int*)(hcat + (size_t)N_NODES * NHID);          // N ints
    unsigned short* nbr_g = (unsigned short*)(cnt_g + N_NODES);   // N*MAXC ushort

    scan_csr<<<N_NODES, 256, 0, stream>>>(adj, cnt_g, nbr_g);
    gemm_k1<<<dim3(96, NHEADS), 256, 0, stream>>>(x, W, a_src, a_dst, Whb, s, t);
    attn_agg<<<N_NODES / 4, 256, 0, stream>>>(adj, Whb, s, t, cnt_g, nbr_g, hcat);
    out_gemm<<<dim3(N_NODES / 64, NEMBED / 64), 256, 0, stream>>>(hcat, lin_w, lin_b, out);
}

// Round 8
// 270.064 us; speedup vs baseline: 1.0973x; 1.0973x over previous
//
#include <hip/hip_runtime.h>
#include <hip/hip_bf16.h>
#include <math.h>

#define N_NODES 6144
#define NFEAT 512
#define NHID 256
#define NHEADS 4
#define DHEAD 64
#define NEMBED 128
#define LRELU_ALPHA 0.2f
#define MAXC 256          // CSR capacity/row; degree ~Binom(6144,1%): mean 61, max~100
#define ASTRIDE 20        // out_gemm As row pad

typedef __attribute__((ext_vector_type(8))) __bf16 bfrag;   // MFMA A/B operand (4 VGPRs)
typedef __attribute__((ext_vector_type(4))) float f32x4;    // MFMA C/D operand
typedef __attribute__((ext_vector_type(4))) int int4v;      // for nontemporal adj loads

// round-to-nearest-even fp32 -> bf16 (bit pattern)
static __device__ __forceinline__ unsigned short f2bf(float f) {
    unsigned u = __float_as_uint(f);
    unsigned r = (u + 0x7FFFu + ((u >> 16) & 1u)) >> 16;
    return (unsigned short)r;
}
static __device__ __forceinline__ float bf2f(unsigned short b) {
    return __uint_as_float((unsigned)b << 16);
}
// Markidis split: v ~= hi + lo, each bf16
static __device__ __forceinline__ void split1(float v, unsigned short& h, unsigned short& l) {
    h = f2bf(v);
    l = f2bf(v - bf2f(h));
}
static __device__ __forceinline__ float bfLo(unsigned u) { return __uint_as_float(u << 16); }
static __device__ __forceinline__ float bfHi(unsigned u) { return __uint_as_float(u & 0xffff0000u); }

// ---------------------------------------------------------------------------
// Kernel 1: grid (96, 68).  [R4 structure — verified best at 275.7 us.
// Co-scheduling the scan with the GEMM is load-bearing: serializing them
// (R5 fused-per-block, R7 separate dispatch) costs +19/+20 us.]
//  y<4 : Wh[h]=x.W[h] via split-bf16 MFMA (3x mfma_f32_16x16x32_bf16 per tile).
//  y>=4: ONE adjacency row per block -> CSR, LDS-atomic count. Adjacency is
//        streamed once with zero reuse -> nontemporal loads keep it from
//        thrashing L2 against the GEMM tiles sharing the CU.
// ---------------------------------------------------------------------------
__global__ __launch_bounds__(256) void gemm_scan(const float* __restrict__ x,
                                                 const float* __restrict__ W,
                                                 const float* __restrict__ a_src,
                                                 const float* __restrict__ a_dst,
                                                 const int* __restrict__ adj,
                                                 unsigned short* __restrict__ Whb,
                                                 float* __restrict__ s_arr,
                                                 float* __restrict__ t_arr,
                                                 int* __restrict__ cnt_g,
                                                 unsigned short* __restrict__ nbr_g) {
    __shared__ unsigned short Ah[64][32];   // x-tile hi  (rows x k)
    __shared__ unsigned short Al[64][32];   // x-tile lo
    __shared__ unsigned short Bh[64][32];   // W-tile hi, TRANSPOSED (n x k), k-block swizzled
    __shared__ unsigned short Bl[64][32];   // W-tile lo
    __shared__ int scnt;
    const int tid = threadIdx.x;

    if (blockIdx.y < NHEADS) {
        // ---------------- MFMA GEMM path ----------------
        const int h = blockIdx.y;
        const int row0 = blockIdx.x * 64;
        const int w = tid >> 6;           // wave id: rows [w*16, w*16+16)
        const int lane = tid & 63;
        const int g = lane >> 4;          // lane group
        const int r = lane & 15;          // lane row-in-group
        const float* Bp = W + (size_t)h * NFEAT * DHEAD;

        f32x4 acc[4] = {};                // acc[nt]: cols nt*16+r, rows w*16+4g+q

        // staging decomposition (wave-uniform per thread)
        const int ar = tid >> 2, akq = (tid & 3) * 8;      // A: row, k-oct base
        const int bkk = tid >> 3, bnq = tid & 7;           // B: k, n-oct
        const int bks = bkk ^ ((bnq & 3) << 3);            // swizzled k-column for B writes

        for (int k0 = 0; k0 < NFEAT; k0 += 32) {
            // ---- stage A: 64x32 fp32 -> bf16 hi/lo ----
            const float4 av0 = *(const float4*)(x + (size_t)(row0 + ar) * NFEAT + k0 + akq);
            const float4 av1 = *(const float4*)(x + (size_t)(row0 + ar) * NFEAT + k0 + akq + 4);
            ushort4 h0, l0, h1, l1;
            split1(av0.x, h0.x, l0.x); split1(av0.y, h0.y, l0.y);
            split1(av0.z, h0.z, l0.z); split1(av0.w, h0.w, l0.w);
            split1(av1.x, h1.x, l1.x); split1(av1.y, h1.y, l1.y);
            split1(av1.z, h1.z, l1.z); split1(av1.w, h1.w, l1.w);
            *(ushort4*)&Ah[ar][akq]     = h0;
            *(ushort4*)&Ah[ar][akq + 4] = h1;
            *(ushort4*)&Al[ar][akq]     = l0;
            *(ushort4*)&Al[ar][akq + 4] = l1;
            // ---- stage B: 32x64 fp32 -> bf16 hi/lo, transposed to [n][k] ----
            const float4 bv0 = *(const float4*)(Bp + (size_t)(k0 + bkk) * DHEAD + bnq * 8);
            const float4 bv1 = *(const float4*)(Bp + (size_t)(k0 + bkk) * DHEAD + bnq * 8 + 4);
            {
                unsigned short hh, ll;
                split1(bv0.x, hh, ll); Bh[bnq * 8 + 0][bks] = hh; Bl[bnq * 8 + 0][bks] = ll;
                split1(bv0.y, hh, ll); Bh[bnq * 8 + 1][bks] = hh; Bl[bnq * 8 + 1][bks] = ll;
                split1(bv0.z, hh, ll); Bh[bnq * 8 + 2][bks] = hh; Bl[bnq * 8 + 2][bks] = ll;
                split1(bv0.w, hh, ll); Bh[bnq * 8 + 3][bks] = hh; Bl[bnq * 8 + 3][bks] = ll;
                split1(bv1.x, hh, ll); Bh[bnq * 8 + 4][bks] = hh; Bl[bnq * 8 + 4][bks] = ll;
                split1(bv1.y, hh, ll); Bh[bnq * 8 + 5][bks] = hh; Bl[bnq * 8 + 5][bks] = ll;
                split1(bv1.z, hh, ll); Bh[bnq * 8 + 6][bks] = hh; Bl[bnq * 8 + 6][bks] = ll;
                split1(bv1.w, hh, ll); Bh[bnq * 8 + 7][bks] = hh; Bl[bnq * 8 + 7][bks] = ll;
            }
            __syncthreads();
            // ---- fragments + MFMA ----
            const int arow = w * 16 + r;
            const bfrag ah = *(const bfrag*)&Ah[arow][g * 8];
            const bfrag al = *(const bfrag*)&Al[arow][g * 8];
#pragma unroll
            for (int nt = 0; nt < 4; nt++) {
                // undo swizzle: stored col c holds logical kk = c ^ sw(n); block-aligned
                const int blk = (g ^ ((2 * nt + (r >> 3)) & 3)) * 8;
                const bfrag bh = *(const bfrag*)&Bh[nt * 16 + r][blk];
                const bfrag bl = *(const bfrag*)&Bl[nt * 16 + r][blk];
                acc[nt] = __builtin_amdgcn_mfma_f32_16x16x32_bf16(ah, bh, acc[nt], 0, 0, 0);
                acc[nt] = __builtin_amdgcn_mfma_f32_16x16x32_bf16(ah, bl, acc[nt], 0, 0, 0);
                acc[nt] = __builtin_amdgcn_mfma_f32_16x16x32_bf16(al, bh, acc[nt], 0, 0, 0);
            }
            __syncthreads();
        }
        // ---- epilogue: Whb bf16 store + fused s/t ----
        // C layout: lane(16g+r) reg q -> row w*16+4g+q, col nt*16+r
        float asv[4], adv[4];
#pragma unroll
        for (int nt = 0; nt < 4; nt++) {
            asv[nt] = a_src[h * DHEAD + nt * 16 + r];
            adv[nt] = a_dst[h * DHEAD + nt * 16 + r];
        }
        const int mbase = row0 + w * 16 + 4 * g;
#pragma unroll
        for (int q = 0; q < 4; q++) {
            const int m = mbase + q;
#pragma unroll
            for (int nt = 0; nt < 4; nt++)
                Whb[((size_t)h * N_NODES + m) * DHEAD + nt * 16 + r] = f2bf(acc[nt][q]);
            float ps = acc[0][q] * asv[0] + acc[1][q] * asv[1] +
                       acc[2][q] * asv[2] + acc[3][q] * asv[3];
            float pt = acc[0][q] * adv[0] + acc[1][q] * adv[1] +
                       acc[2][q] * adv[2] + acc[3][q] * adv[3];
#pragma unroll
            for (int off = 1; off < 16; off <<= 1) {   // reduce over r (stays in group)
                ps += __shfl_xor(ps, off);
                pt += __shfl_xor(pt, off);
            }
            if (r == 0) {
                s_arr[h * N_NODES + m] = ps;
                t_arr[h * N_NODES + m] = pt;
            }
        }
    } else {
        // ---------------- scan path: one row per block, LDS-atomic count ------
        const int rr = (blockIdx.y - NHEADS) * gridDim.x + blockIdx.x; // 0..6143
        const int* arow = adj + (size_t)rr * N_NODES;
        unsigned short* nrow = nbr_g + (size_t)rr * MAXC;
        if (tid == 0) scnt = 0;
        __syncthreads();
#pragma unroll
        for (int it = 0; it < 6; ++it) {
            const int j0 = it * 1024 + tid * 4;
            const int4v v = __builtin_nontemporal_load((const int4v*)(arow + j0));
            const int n = (v.x != 0) + (v.y != 0) + (v.z != 0) + (v.w != 0);
            if (n) {
                int base = atomicAdd(&scnt, n);
                if (v.x) { if (base < MAXC) nrow[base] = (unsigned short)j0; ++base; }
                if (v.y) { if (base < MAXC) nrow[base] = (unsigned short)(j0 + 1); ++base; }
                if (v.z) { if (base < MAXC) nrow[base] = (unsigned short)(j0 + 2); ++base; }
                if (v.w) { if (base < MAXC) nrow[base] = (unsigned short)(j0 + 3); }
            }
        }
        __syncthreads();
        if (tid == 0) cnt_g[rr] = scnt;
    }
}

// ---------------------------------------------------------------------------
// Kernel 2: CSR attention. Block = dst node i; wave = head. Quad bf16 gather.
// [R4 version, verified]
// ---------------------------------------------------------------------------
__global__ __launch_bounds__(256) void attn_agg(const int* __restrict__ adj,
                                                const unsigned short* __restrict__ Whb,
                                                const float* __restrict__ s_arr,
                                                const float* __restrict__ t_arr,
                                                const int* __restrict__ cnt_g,
                                                const unsigned short* __restrict__ nbr_g,
                                                float* __restrict__ hcat) {
    __shared__ unsigned short nbr[MAXC];
    __shared__ float p_s[NHEADS][MAXC];
    const int i = blockIdx.x;
    const int tid = threadIdx.x;
    const int h = tid >> 6;
    const int lane = tid & 63;
    const int q = lane >> 4;          // which neighbor of the quad this lane serves
    const int dq = (lane & 15) * 4;   // 4-wide d-slice this lane accumulates
    const int c = cnt_g[i];
    const unsigned short* wp = Whb + (size_t)h * N_NODES * DHEAD;

    float b0[4] = {0.f, 0.f, 0.f, 0.f};
    float l = 1.0f;
    bool combine = true;

    if (c > 0 && c <= MAXC) {
        for (int k = tid; k < c; k += 256) nbr[k] = nbr_g[(size_t)i * MAXC + k];
        __syncthreads();

        const float s_h = s_arr[h * N_NODES + i];
        const float* tp = t_arr + (size_t)h * N_NODES;
        float m = -INFINITY;
        for (int k = lane; k < c; k += 64) {
            float e = s_h + tp[nbr[k]];
            e = e >= 0.0f ? e : LRELU_ALPHA * e;
            p_s[h][k] = e;
            m = fmaxf(m, e);
        }
#pragma unroll
        for (int off = 32; off > 0; off >>= 1) m = fmaxf(m, __shfl_xor(m, off));
        float ls = 0.0f;
        for (int k = lane; k < c; k += 64) {
            const float p = __expf(p_s[h][k] - m);
            p_s[h][k] = p;
            ls += p;
        }
#pragma unroll
        for (int off = 32; off > 0; off >>= 1) ls += __shfl_xor(ls, off);
        l = ls;
        // p_s[h] is wave-private: no barrier needed.

        float b1[4] = {0.f, 0.f, 0.f, 0.f};
        float b2[4] = {0.f, 0.f, 0.f, 0.f};
        float b3[4] = {0.f, 0.f, 0.f, 0.f};
        int k = 0;
        for (; k + 16 <= c; k += 16) {   // 16 neighbors / iter = 4 wave loads
            const int k0 = k + q, k1 = k + 4 + q, k2 = k + 8 + q, k3 = k + 12 + q;
            const int j0 = nbr[k0], j1 = nbr[k1], j2 = nbr[k2], j3 = nbr[k3];
            const float p0 = p_s[h][k0], p1 = p_s[h][k1];
            const float p2 = p_s[h][k2], p3 = p_s[h][k3];
            const uint2 w0 = *(const uint2*)(wp + (size_t)j0 * DHEAD + dq);
            const uint2 w1 = *(const uint2*)(wp + (size_t)j1 * DHEAD + dq);
            const uint2 w2 = *(const uint2*)(wp + (size_t)j2 * DHEAD + dq);
            const uint2 w3 = *(const uint2*)(wp + (size_t)j3 * DHEAD + dq);
            b0[0] += p0 * bfLo(w0.x); b0[1] += p0 * bfHi(w0.x);
            b0[2] += p0 * bfLo(w0.y); b0[3] += p0 * bfHi(w0.y);
            b1[0] += p1 * bfLo(w1.x); b1[1] += p1 * bfHi(w1.x);
            b1[2] += p1 * bfLo(w1.y); b1[3] += p1 * bfHi(w1.y);
            b2[0] += p2 * bfLo(w2.x); b2[1] += p2 * bfHi(w2.x);
            b2[2] += p2 * bfLo(w2.y); b2[3] += p2 * bfHi(w2.y);
            b3[0] += p3 * bfLo(w3.x); b3[1] += p3 * bfHi(w3.x);
            b3[2] += p3 * bfLo(w3.y); b3[3] += p3 * bfHi(w3.y);
        }
        for (; k < c; k += 4) {          // quad tail
            const int kk = k + q;
            const int j = (kk < c) ? nbr[kk] : nbr[k];
            const float p = (kk < c) ? p_s[h][kk] : 0.0f;
            const uint2 w = *(const uint2*)(wp + (size_t)j * DHEAD + dq);
            b0[0] += p * bfLo(w.x); b0[1] += p * bfHi(w.x);
            b0[2] += p * bfLo(w.y); b0[3] += p * bfHi(w.y);
        }
#pragma unroll
        for (int d = 0; d < 4; d++) b0[d] = (b0[d] + b1[d]) + (b2[d] + b3[d]);
    } else if (c == 0) {
        // empty row: softmax over uniform -9e15 logits -> mean of Wh (never at 1%)
        for (int j = q; j < N_NODES; j += 4) {
            const uint2 w = *(const uint2*)(wp + (size_t)j * DHEAD + dq);
            b0[0] += bfLo(w.x); b0[1] += bfHi(w.x);
            b0[2] += bfLo(w.y); b0[3] += bfHi(w.y);
        }
        l = (float)N_NODES;
    } else {
        // c > MAXC: serial online-softmax rescan; all q-replicas identical.
        combine = false;
        const int* arow = adj + (size_t)i * N_NODES;
        const float s_h = s_arr[h * N_NODES + i];
        const float* tp = t_arr + (size_t)h * N_NODES;
        float m = -INFINITY, ll = 0.0f;
        for (int j = 0; j < N_NODES; j++) {
            if (arow[j]) {
                float e = s_h + tp[j];
                e = e >= 0.0f ? e : LRELU_ALPHA * e;
                const float m_new = fmaxf(m, e);
                const float scale = __expf(m - m_new);
                const float p = __expf(e - m_new);
                ll = ll * scale + p;
                const uint2 w = *(const uint2*)(wp + (size_t)j * DHEAD + dq);
                b0[0] = b0[0] * scale + p * bfLo(w.x);
                b0[1] = b0[1] * scale + p * bfHi(w.x);
                b0[2] = b0[2] * scale + p * bfLo(w.y);
                b0[3] = b0[3] * scale + p * bfHi(w.y);
                m = m_new;
            }
        }
        l = ll;
    }

    if (combine) {
#pragma unroll
        for (int d = 0; d < 4; d++) {
            b0[d] += __shfl_xor(b0[d], 16);
            b0[d] += __shfl_xor(b0[d], 32);
        }
    }
    // per-head ELU, write hcat row slice (16 lanes x 16B = 256B coalesced/head)
    if (lane < 16) {
        float4 hv;
        float* pv = &hv.x;
#pragma unroll
        for (int d = 0; d < 4; d++) {
            float v = b0[d] / l;
            pv[d] = v > 0.0f ? v : expm1f(v);
        }
        *(float4*)(hcat + (size_t)i * NHID + h * DHEAD + dq) = hv;
    }
}

// ---------------------------------------------------------------------------
// Kernel 3: out = elu(hcat @ lin_w^T + b)
// ---------------------------------------------------------------------------
__global__ __launch_bounds__(256) void out_gemm(const float* __restrict__ hcat,
                                                const float* __restrict__ lin_w,
                                                const float* __restrict__ lin_b,
                                                float* __restrict__ out) {
    __shared__ float As[64][ASTRIDE * 4];
    __shared__ float Bs[16][64];
    const int tid = threadIdx.x;
    const int tx = tid & 15;
    const int ty = tid >> 4;
    const int row0 = blockIdx.x * 64;
    const int c0 = blockIdx.y * 64;

    float acc[4][4] = {};

    for (int k0 = 0; k0 < NHID; k0 += 16) {
        {
            const int r = tid >> 2, kq = tid & 3;
            const float4 v = *(const float4*)(hcat + (size_t)(row0 + r) * NHID + k0 + kq * 4);
            *(float4*)&As[r][kq * 4] = v;
        }
        {
            const int cc = tid & 63, kq = tid >> 6;
            const float4 v = *(const float4*)(lin_w + (size_t)(c0 + cc) * NHID + k0 + kq * 4);
            Bs[kq * 4 + 0][cc] = v.x;
            Bs[kq * 4 + 1][cc] = v.y;
            Bs[kq * 4 + 2][cc] = v.z;
            Bs[kq * 4 + 3][cc] = v.w;
        }
        __syncthreads();
#pragma unroll
        for (int kk = 0; kk < 16; kk++) {
            float a[4], b[4];
#pragma unroll
            for (int i = 0; i < 4; i++) a[i] = As[ty * 4 + i][kk];
#pragma unroll
            for (int j = 0; j < 4; j++) b[j] = Bs[kk][tx * 4 + j];
#pragma unroll
            for (int i = 0; i < 4; i++)
#pragma unroll
                for (int j = 0; j < 4; j++) acc[i][j] += a[i] * b[j];
        }
        __syncthreads();
    }
#pragma unroll
    for (int i = 0; i < 4; i++) {
        const int row = row0 + ty * 4 + i;
        float v[4];
#pragma unroll
        for (int j = 0; j < 4; j++) {
            const int col = c0 + tx * 4 + j;
            float val = acc[i][j] + lin_b[col];
            v[j] = val > 0.0f ? val : expm1f(val);
        }
        *(float4*)(out + (size_t)row * NEMBED + c0 + tx * 4) =
            make_float4(v[0], v[1], v[2], v[3]);
    }
}

extern "C" void kernel_launch(void* const* d_in, const int* in_sizes, int n_in,
                              void* d_out, int out_size, void* d_ws, size_t ws_size,
                              hipStream_t stream) {
    const float* x     = (const float*)d_in[0];
    const int*   adj   = (const int*)d_in[1];
    const float* W     = (const float*)d_in[2];
    const float* a_src = (const float*)d_in[3];
    const float* a_dst = (const float*)d_in[4];
    const float* lin_w = (const float*)d_in[5];
    const float* lin_b = (const float*)d_in[6];
    float* out = (float*)d_out;

    unsigned short* Whb = (unsigned short*)d_ws;                  // H*N*D bf16 (3.1 MB)
    float* s    = (float*)(Whb + (size_t)NHEADS * N_NODES * DHEAD);
    float* t    = s + (size_t)NHEADS * N_NODES;
    float* hcat = t + (size_t)NHEADS * N_NODES;                   // N*NHID floats
    int* cnt_g  = (int*)(hcat + (size_t)N_NODES * NHID);          // N ints
    unsigned short* nbr_g = (unsigned short*)(cnt_g + N_NODES);   // N*MAXC ushort

    gemm_scan<<<dim3(96, NHEADS + 64), 256, 0, stream>>>(
        x, W, a_src, a_dst, adj, Whb, s, t, cnt_g, nbr_g);
    attn_agg<<<N_NODES, 256, 0, stream>>>(adj, Whb, s, t, cnt_g, nbr_g, hcat);
    out_gemm<<<dim3(N_NODES / 64, NEMBED / 64), 256, 0, stream>>>(hcat, lin_w, lin_b, out);
}